// Round 1
// baseline (986.646 us; speedup 1.0000x reference)
//
#include <hip/hip_runtime.h>
#include <math.h>

#define B_ 2
#define L_ 2048
#define DM_ 512
#define H_ 8
#define DK_ 64
#define SCALE_ 0.125f   // 1/sqrt(64)

// Select float4 component with compile-time kk (loops are unrolled).
#define PF4(v, kk) ((kk) == 0 ? (v).x : (kk) == 1 ? (v).y : (kk) == 2 ? (v).z : (v).w)

// ---------------------------------------------------------------------------
// GEMM: C[m,n] = sum_k X[m,k] * W[n,k] + bias[n];  M=4096 (B*L), N=K=512.
// head_major=1: write out[((b*H + n/64)*L + l)*64 + (n&63)]  (q/k/v layout)
// head_major=0: write out[m*512 + n]                          (final output)
// 64x64 tile, 256 threads, 4x4 micro-tile with i = ty + 16r (bank-friendly).
// ---------------------------------------------------------------------------
__global__ __launch_bounds__(256)
void gemm_xwt(const float* __restrict__ X, const float* __restrict__ W,
              const float* __restrict__ bias, float* __restrict__ out,
              int head_major)
{
    __shared__ float As[64][36];  // stride 36 floats = 144B: 16B-aligned, 36%32=4 -> 2-way max
    __shared__ float Bs[64][36];
    const int t  = threadIdx.x;
    const int ty = t >> 4, tx = t & 15;
    const int m0 = blockIdx.x * 64, n0 = blockIdx.y * 64;

    float acc[4][4] = {};

    for (int k0 = 0; k0 < DM_; k0 += 32) {
        // load 64x32 tiles of X and W (reduction dim contiguous for both)
        #pragma unroll
        for (int rr = 0; rr < 2; ++rr) {
            const int i  = rr * 32 + (t >> 3);
            const int c4 = (t & 7) * 4;
            *(float4*)&As[i][c4] = *(const float4*)&X[(size_t)(m0 + i) * DM_ + k0 + c4];
            *(float4*)&Bs[i][c4] = *(const float4*)&W[(size_t)(n0 + i) * DM_ + k0 + c4];
        }
        __syncthreads();
        #pragma unroll
        for (int kk = 0; kk < 32; kk += 4) {
            float4 af[4], bf[4];
            #pragma unroll
            for (int r = 0; r < 4; ++r) af[r] = *(const float4*)&As[ty + 16*r][kk];
            #pragma unroll
            for (int c = 0; c < 4; ++c) bf[c] = *(const float4*)&Bs[tx + 16*c][kk];
            #pragma unroll
            for (int r = 0; r < 4; ++r)
                #pragma unroll
                for (int c = 0; c < 4; ++c)
                    acc[r][c] += af[r].x * bf[c].x + af[r].y * bf[c].y
                               + af[r].z * bf[c].z + af[r].w * bf[c].w;
        }
        __syncthreads();
    }

    #pragma unroll
    for (int r = 0; r < 4; ++r) {
        const int m  = m0 + ty + 16*r;
        const int bb = m / L_, l = m % L_;
        #pragma unroll
        for (int c = 0; c < 4; ++c) {
            const int n   = n0 + tx + 16*c;
            const float v = acc[r][c] + bias[n];
            if (head_major) {
                out[(((size_t)bb * H_ + (n >> 6)) * L_ + l) * DK_ + (n & 63)] = v;
            } else {
                out[(size_t)m * DM_ + n] = v;
            }
        }
    }
}

// ---------------------------------------------------------------------------
// Flash attention, fp32. q/k/v: [B,H,L,DK].  ctx out: [B,L,H*DK].
// Block: 256 threads, 64-query tile; iterate 32 K/V tiles of 64 with online
// softmax. 4x4 micro-tile, rows i = ty+16r (pad-68 rows -> <=2-way LDS).
// ---------------------------------------------------------------------------
__global__ __launch_bounds__(256)
void flash_attn(const float* __restrict__ qg, const float* __restrict__ kg,
                const float* __restrict__ vg, float* __restrict__ ctx)
{
    __shared__ float Qs[64][68];   // row stride 272B: 16B-aligned, 68%32=4
    __shared__ float Ks[64][68];
    __shared__ float Vs[64][68];
    __shared__ float Ps[64][68];
    __shared__ float red[64][20];
    __shared__ float fs[64];
    __shared__ float ms[64];

    const int t  = threadIdx.x;
    const int ty = t >> 4, tx = t & 15;
    const int qt = blockIdx.x;     // 0..31
    const int bh = blockIdx.y;     // 0..15  (= b*H + h)

    const float* qp = qg + ((size_t)bh * L_ + qt * 64) * DK_;
    const float* kp = kg + (size_t)bh * L_ * DK_;
    const float* vp = vg + (size_t)bh * L_ * DK_;

    // Load Q tile once, pre-scaled by 1/sqrt(DK)
    #pragma unroll
    for (int rr = 0; rr < 4; ++rr) {
        const int i = rr * 16 + ty;
        float4 a = *(const float4*)&qp[i * DK_ + tx * 4];
        a.x *= SCALE_; a.y *= SCALE_; a.z *= SCALE_; a.w *= SCALE_;
        *(float4*)&Qs[i][tx * 4] = a;
    }

    float o[4][4] = {};
    float m_run = -INFINITY, l_run = 0.0f;

    for (int kt = 0; kt < L_ / 64; ++kt) {
        __syncthreads();  // previous iteration's readers of Ks/Vs/Ps done (also Qs visible, iter 0)
        #pragma unroll
        for (int rr = 0; rr < 4; ++rr) {
            const int i = rr * 16 + ty;
            *(float4*)&Ks[i][tx*4] = *(const float4*)&kp[(size_t)(kt*64 + i) * DK_ + tx*4];
            *(float4*)&Vs[i][tx*4] = *(const float4*)&vp[(size_t)(kt*64 + i) * DK_ + tx*4];
        }
        __syncthreads();

        // S = (Q*scale) K^T
        float s[4][4] = {};
        #pragma unroll
        for (int d0 = 0; d0 < DK_; d0 += 4) {
            float4 qf[4], kf[4];
            #pragma unroll
            for (int r = 0; r < 4; ++r) qf[r] = *(const float4*)&Qs[ty + 16*r][d0];
            #pragma unroll
            for (int c = 0; c < 4; ++c) kf[c] = *(const float4*)&Ks[tx + 16*c][d0];
            #pragma unroll
            for (int r = 0; r < 4; ++r)
                #pragma unroll
                for (int c = 0; c < 4; ++c)
                    s[r][c] += qf[r].x * kf[c].x + qf[r].y * kf[c].y
                             + qf[r].z * kf[c].z + qf[r].w * kf[c].w;
        }

        // partial row max
        #pragma unroll
        for (int r = 0; r < 4; ++r) {
            const float pm = fmaxf(fmaxf(s[r][0], s[r][1]), fmaxf(s[r][2], s[r][3]));
            red[ty + 16*r][tx] = pm;
        }
        __syncthreads();

        if (t < 64) {
            float mt = red[t][0];
            #pragma unroll
            for (int j = 1; j < 16; ++j) mt = fmaxf(mt, red[t][j]);
            const float mn = fmaxf(m_run, mt);
            fs[t] = __expf(m_run - mn);   // first tile: exp(-inf) = 0
            ms[t] = mn;
            m_run = mn;
        }
        __syncthreads();

        // P = exp(S - m_new), partial row sums
        #pragma unroll
        for (int r = 0; r < 4; ++r) {
            const float mi = ms[ty + 16*r];
            float psum = 0.f;
            #pragma unroll
            for (int c = 0; c < 4; ++c) {
                const float p = __expf(s[r][c] - mi);
                Ps[ty + 16*r][tx + 16*c] = p;
                psum += p;
            }
            red[ty + 16*r][tx] = psum;
        }
        __syncthreads();

        // O = O*f + P @ V
        #pragma unroll
        for (int r = 0; r < 4; ++r) {
            const float f = fs[ty + 16*r];
            #pragma unroll
            for (int c = 0; c < 4; ++c) o[r][c] *= f;
        }
        #pragma unroll
        for (int k0 = 0; k0 < 64; k0 += 4) {
            float4 pf[4];
            #pragma unroll
            for (int r = 0; r < 4; ++r) pf[r] = *(const float4*)&Ps[ty + 16*r][k0];
            #pragma unroll
            for (int kk = 0; kk < 4; ++kk) {
                #pragma unroll
                for (int c = 0; c < 4; ++c) {
                    const float vv = Vs[k0 + kk][tx + 16*c];
                    #pragma unroll
                    for (int r = 0; r < 4; ++r) o[r][c] += PF4(pf[r], kk) * vv;
                }
            }
        }
        if (t < 64) {
            float ls = 0.f;
            #pragma unroll
            for (int j = 0; j < 16; ++j) ls += red[t][j];
            l_run = l_run * fs[t] + ls;
        }
    }

    __syncthreads();
    if (t < 64) fs[t] = 1.0f / l_run;
    __syncthreads();

    const int b = bh >> 3, h = bh & 7;
    float* cp = ctx + ((size_t)b * L_ + qt * 64) * DM_ + h * DK_;
    #pragma unroll
    for (int r = 0; r < 4; ++r) {
        const float inv = fs[ty + 16*r];
        #pragma unroll
        for (int c = 0; c < 4; ++c)
            cp[(size_t)(ty + 16*r) * DM_ + tx + 16*c] = o[r][c] * inv;
    }
}

// ---------------------------------------------------------------------------
extern "C" void kernel_launch(void* const* d_in, const int* in_sizes, int n_in,
                              void* d_out, int out_size, void* d_ws, size_t ws_size,
                              hipStream_t stream)
{
    const float* Q  = (const float*)d_in[0];
    const float* K  = (const float*)d_in[1];
    const float* V  = (const float*)d_in[2];
    const float* Wq = (const float*)d_in[3];
    const float* bq = (const float*)d_in[4];
    const float* Wk = (const float*)d_in[5];
    const float* bk = (const float*)d_in[6];
    const float* Wv = (const float*)d_in[7];
    const float* bv = (const float*)d_in[8];
    const float* Wo = (const float*)d_in[9];
    const float* bo = (const float*)d_in[10];
    // d_in[11] = index_sample: provably unused (n_top == L -> top_k is a
    // permutation -> the scatter overwrites the whole mean-context baseline).

    float* ws = (float*)d_ws;
    const size_t NQ = (size_t)B_ * H_ * L_ * DK_;   // 2,097,152 floats
    float* qw = ws;
    float* kw = ws + NQ;
    float* vw = ws + 2 * NQ;
    float* cw = ws + 3 * NQ;   // total 32 MB of d_ws

    dim3 gg(64, 8), blk(256);
    gemm_xwt<<<gg, blk, 0, stream>>>(Q, Wq, bq, qw, 1);
    gemm_xwt<<<gg, blk, 0, stream>>>(K, Wk, bk, kw, 1);
    gemm_xwt<<<gg, blk, 0, stream>>>(V, Wv, bv, vw, 1);

    dim3 ga(L_ / 64, B_ * H_);
    flash_attn<<<ga, blk, 0, stream>>>(qw, kw, vw, cw);

    gemm_xwt<<<gg, blk, 0, stream>>>(cw, Wo, bo, (float*)d_out, 0);
}

// Round 2
// 198.359 us; speedup vs baseline: 4.9741x; 4.9741x over previous
//
#include <hip/hip_runtime.h>
#include <hip/hip_bf16.h>
#include <math.h>

#define B_ 2
#define L_ 2048
#define DM_ 512
#define H_ 8
#define DK_ 64
#define SCALE_ 0.125f   // 1/sqrt(64), folded into Q projection epilogue

typedef __attribute__((ext_vector_type(8))) short short8;      // MFMA bf16 A/B frag (guide §3)
typedef __attribute__((ext_vector_type(8))) unsigned short ushort8;
typedef __attribute__((ext_vector_type(4))) float f32x4;       // MFMA C/D frag
typedef unsigned short u16;

__device__ __forceinline__ u16 f2bf(float x) {
    __hip_bfloat16 h = __float2bfloat16(x);
    u16 r; __builtin_memcpy(&r, &h, 2); return r;
}

// async global->LDS, 16B/lane; LDS dest is wave-uniform base + laneInWave*16
__device__ __forceinline__ void gld16(const u16* g, u16* l) {
    __builtin_amdgcn_global_load_lds(
        (const __attribute__((address_space(1))) void*)g,
        (__attribute__((address_space(3))) void*)l, 16, 0, 0);
}

// ---------------------------------------------------------------------------
// Fused fp32->bf16 conversion: Q,K,V (2M elems each) + Wq,Wk,Wv,Wo (256K each)
// into one contiguous bf16 region of ws. 8 elems/thread.
// ---------------------------------------------------------------------------
__global__ __launch_bounds__(256)
void cvt7(const float* __restrict__ s0, const float* __restrict__ s1,
          const float* __restrict__ s2, const float* __restrict__ s3,
          const float* __restrict__ s4, const float* __restrict__ s5,
          const float* __restrict__ s6, u16* __restrict__ dst)
{
    const size_t NB = 2097152, NW = 262144;
    size_t i = ((size_t)blockIdx.x * 256 + threadIdx.x) * 8;
    const float* s; size_t off;
    if      (i < NB)          { s = s0; off = 0; }
    else if (i < 2*NB)        { s = s1; off = NB; }
    else if (i < 3*NB)        { s = s2; off = 2*NB; }
    else if (i < 3*NB + NW)   { s = s3; off = 3*NB; }
    else if (i < 3*NB + 2*NW) { s = s4; off = 3*NB + NW; }
    else if (i < 3*NB + 3*NW) { s = s5; off = 3*NB + 2*NW; }
    else                      { s = s6; off = 3*NB + 3*NW; }
    const float* p = s + (i - off);
    float4 x = *(const float4*)p;
    float4 y = *(const float4*)(p + 4);
    ushort8 o;
    o[0]=f2bf(x.x); o[1]=f2bf(x.y); o[2]=f2bf(x.z); o[3]=f2bf(x.w);
    o[4]=f2bf(y.x); o[5]=f2bf(y.y); o[6]=f2bf(y.z); o[7]=f2bf(y.w);
    *(ushort8*)&dst[i] = o;
}

// ---------------------------------------------------------------------------
// bf16 MFMA GEMM: C[m,n] = sum_k X[m,k]*W[n,k] + bias[n]; M=4096, N=K=512.
// 64x64 tile, BK=64, 4 waves; wave w owns rows w*16..w*16+15.
// LDS tiles are LINEAR [64 rows][64 cols] bf16 (128B rows) staged by
// global_load_lds with the 16B-chunk XOR swizzle (slot c holds global chunk
// c^(row&7)) -> conflict-free-ish ds_read_b128 fragments.
// MODE 0: fp32 out [m][512]          (final projection)
// MODE 1: bf16 out [B,H,L,DK], *scale (q with 0.125, k with 1.0)
// MODE 2: bf16 out [B,H,DK,L]         (v, pre-transposed for attention PV)
// ---------------------------------------------------------------------------
template<int MODE>
__global__ __launch_bounds__(256)
void gemm_mfma(const u16* __restrict__ X, const u16* __restrict__ W,
               const float* __restrict__ bias, void* __restrict__ outv,
               float scale)
{
    __shared__ u16 Xs[64*64];
    __shared__ u16 Ws[64*64];
    __shared__ u16 Ts[(MODE==2) ? 64*66 : 64];   // mode-2 transpose buffer (pad 66)

    const int t = threadIdx.x;
    const int w = t >> 6, lw = t & 63;
    const int g = lw >> 4, c15 = lw & 15;
    const int m0 = blockIdx.x * 64, n0 = blockIdx.y * 64;

    f32x4 acc[4];
    #pragma unroll
    for (int nt = 0; nt < 4; ++nt) acc[nt] = f32x4{0.f,0.f,0.f,0.f};

    const int rs0 = w*8 + (lw >> 3);   // staging row this lane covers (j=0)
    const int cs0 = lw & 7;            // staging LDS chunk slot
    const int arow = w*16 + c15;       // A-frag row (A: row = lane&15)

    for (int k0 = 0; k0 < DM_; k0 += 64) {
        __syncthreads();               // prev-iter readers done before overwrite
        #pragma unroll
        for (int j = 0; j < 2; ++j) {
            const int r = rs0 + j*32;
            const int csrc = (cs0 ^ (r & 7)) * 8;   // pre-swizzled global chunk
            gld16(X + (size_t)(m0 + r)*DM_ + k0 + csrc, &Xs[w*512 + j*2048]);
            gld16(W + (size_t)(n0 + r)*DM_ + k0 + csrc, &Ws[w*512 + j*2048]);
        }
        __syncthreads();               // drains vmcnt(0): tiles landed
        #pragma unroll
        for (int ks = 0; ks < 2; ++ks) {
            short8 a = *(const short8*)&Xs[arow*64 + (((ks*4 + g) ^ (arow & 7)) * 8)];
            #pragma unroll
            for (int nt = 0; nt < 4; ++nt) {
                const int brow = nt*16 + c15;       // B: col = lane&15
                short8 b = *(const short8*)&Ws[brow*64 + (((ks*4 + g) ^ (brow & 7)) * 8)];
                acc[nt] = __builtin_amdgcn_mfma_f32_16x16x32_bf16(a, b, acc[nt], 0, 0, 0);
            }
        }
    }

    // C/D layout: row = 4*(lane>>4)+reg, col = lane&15  (m89-verified)
    if (MODE == 0) {
        float* out = (float*)outv;
        #pragma unroll
        for (int nt = 0; nt < 4; ++nt) {
            const int n = n0 + nt*16 + c15;
            const float bv = bias[n];
            #pragma unroll
            for (int reg = 0; reg < 4; ++reg) {
                const int m = m0 + w*16 + 4*g + reg;
                out[(size_t)m * DM_ + n] = acc[nt][reg] + bv;
            }
        }
    } else if (MODE == 1) {
        u16* out = (u16*)outv;
        const int h  = n0 >> 6;          // one head per n-block (64-aligned)
        const int bb = m0 >> 11;         // batch (L=2048 rows per batch)
        const int l0 = m0 & (L_ - 1);
        #pragma unroll
        for (int nt = 0; nt < 4; ++nt) {
            const int dk = nt*16 + c15;
            const float bv = bias[n0 + dk];
            #pragma unroll
            for (int reg = 0; reg < 4; ++reg) {
                const int l = l0 + w*16 + 4*g + reg;
                out[(((size_t)bb*H_ + h)*L_ + l)*DK_ + dk] =
                    f2bf((acc[nt][reg] + bv) * scale);
            }
        }
    } else {  // MODE 2: transpose through LDS, store [B,H,DK,L] coalesced
        u16* out = (u16*)outv;
        const int h  = n0 >> 6;
        const int bb = m0 >> 11;
        const int l0 = m0 & (L_ - 1);
        #pragma unroll
        for (int nt = 0; nt < 4; ++nt) {
            const int dk = nt*16 + c15;
            const float bv = bias[n0 + dk];
            #pragma unroll
            for (int reg = 0; reg < 4; ++reg)
                Ts[(w*16 + 4*g + reg)*66 + dk] = f2bf(acc[nt][reg] + bv);
        }
        __syncthreads();
        const int dk = t >> 2, q = t & 3;
        ushort8 o0, o1;
        #pragma unroll
        for (int i = 0; i < 8; ++i) o0[i] = Ts[(q*16 + i)*66 + dk];
        #pragma unroll
        for (int i = 0; i < 8; ++i) o1[i] = Ts[(q*16 + 8 + i)*66 + dk];
        const size_t base = (((size_t)bb*H_ + h)*DK_ + dk)*L_ + l0 + q*16;
        *(ushort8*)&out[base]     = o0;
        *(ushort8*)&out[base + 8] = o1;
    }
}

// ---------------------------------------------------------------------------
// Flash attention, bf16 MFMA, fp32 accum. q,k: [B,H,L,DK]; vT: [B,H,DK,L];
// ctx out bf16 [B,L,H*DK]. Grid (32 q-tiles, 16 bh); 4 waves x 16 q-rows.
// Q frags in registers (loaded once, pre-scaled at projection). Per 64-key
// tile: S via 8 MFMA, online softmax with shfl_xor row reduce (rows live in
// lanes (lane>>4) group, cols in lane&15 per C-layout), P through per-wave
// pad-68 fp32 LDS (C-layout -> A-frag layout conversion), PV via 8 MFMA.
// ---------------------------------------------------------------------------
__global__ __launch_bounds__(256)
void attn_mfma(const u16* __restrict__ qg, const u16* __restrict__ kg,
               const u16* __restrict__ vtg, u16* __restrict__ ctx)
{
    __shared__ u16 Ks[64*64];
    __shared__ u16 Vs[64*64];
    __shared__ float Ps[4][16*68];

    const int t = threadIdx.x;
    const int w = t >> 6, lw = t & 63;
    const int g = lw >> 4, c15 = lw & 15;
    const int qt = blockIdx.x, bh = blockIdx.y;

    const u16* qp = qg + ((size_t)bh*L_ + qt*64 + w*16) * DK_;
    const u16* kp = kg + (size_t)bh*L_*DK_;
    const u16* vp = vtg + (size_t)bh*DK_*L_;

    // A-frag: row = lane&15, k = (lane>>4)*8 + j  (same mapping as B loads ->
    // position-wise MFMA pairing is correct regardless of HW k permutation)
    short8 qf0 = *(const short8*)&qp[c15*DK_ + g*8];
    short8 qf1 = *(const short8*)&qp[c15*DK_ + 32 + g*8];

    f32x4 o[4];
    #pragma unroll
    for (int dt = 0; dt < 4; ++dt) o[dt] = f32x4{0.f,0.f,0.f,0.f};
    float m_run[4] = {-1e30f,-1e30f,-1e30f,-1e30f};
    float l_run[4] = {0.f,0.f,0.f,0.f};

    const int rs0 = w*8 + (lw >> 3);
    const int cs0 = lw & 7;
    float* Pw = &Ps[w][0];

    for (int kt = 0; kt < L_/64; ++kt) {
        __syncthreads();
        #pragma unroll
        for (int j = 0; j < 2; ++j) {
            const int r = rs0 + j*32;
            const int csrc = (cs0 ^ (r & 7)) * 8;
            gld16(kp + (size_t)(kt*64 + r)*DK_ + csrc, &Ks[w*512 + j*2048]);  // keys x dk
            gld16(vp + (size_t)r*L_ + kt*64 + csrc,    &Vs[w*512 + j*2048]);  // dk x keys
        }
        __syncthreads();

        // S = Q K^T  (16 q-rows x 64 keys per wave)
        f32x4 s[4];
        #pragma unroll
        for (int nt = 0; nt < 4; ++nt) s[nt] = f32x4{0.f,0.f,0.f,0.f};
        #pragma unroll
        for (int ks = 0; ks < 2; ++ks) {
            short8 aq = ks ? qf1 : qf0;
            #pragma unroll
            for (int nt = 0; nt < 4; ++nt) {
                const int key = nt*16 + c15;
                short8 b = *(const short8*)&Ks[key*64 + (((ks*4 + g) ^ (key & 7)) * 8)];
                s[nt] = __builtin_amdgcn_mfma_f32_16x16x32_bf16(aq, b, s[nt], 0, 0, 0);
            }
        }

        // online softmax; row r=4g+reg lives in the 16 lanes sharing lane>>4
        float mx[4], fr[4], ps[4];
        #pragma unroll
        for (int reg = 0; reg < 4; ++reg)
            mx[reg] = fmaxf(fmaxf(s[0][reg], s[1][reg]), fmaxf(s[2][reg], s[3][reg]));
        #pragma unroll
        for (int off = 1; off < 16; off <<= 1) {
            #pragma unroll
            for (int reg = 0; reg < 4; ++reg)
                mx[reg] = fmaxf(mx[reg], __shfl_xor(mx[reg], off, 64));
        }
        #pragma unroll
        for (int reg = 0; reg < 4; ++reg) {
            const float mn = fmaxf(m_run[reg], mx[reg]);
            fr[reg] = __expf(m_run[reg] - mn);
            m_run[reg] = mn;
            ps[reg] = 0.f;
        }
        #pragma unroll
        for (int nt = 0; nt < 4; ++nt) {
            #pragma unroll
            for (int reg = 0; reg < 4; ++reg) {
                const float p = __expf(s[nt][reg] - m_run[reg]);
                Pw[(4*g + reg)*68 + nt*16 + c15] = p;   // C-layout position
                ps[reg] += p;
            }
        }
        #pragma unroll
        for (int off = 1; off < 16; off <<= 1) {
            #pragma unroll
            for (int reg = 0; reg < 4; ++reg)
                ps[reg] += __shfl_xor(ps[reg], off, 64);
        }
        f32x4 fv; fv[0]=fr[0]; fv[1]=fr[1]; fv[2]=fr[2]; fv[3]=fr[3];
        #pragma unroll
        for (int reg = 0; reg < 4; ++reg)
            l_run[reg] = l_run[reg]*fr[reg] + ps[reg];
        #pragma unroll
        for (int dt = 0; dt < 4; ++dt) o[dt] *= fv;

        // PV: A-frag of P from LDS (row = lane&15), V B-frag from swizzled Vs.
        // Same-wave LDS write->read: DS pipe is in-order per wave; compiler
        // orders via lgkmcnt on the aliasing Ps array.
        #pragma unroll
        for (int ks = 0; ks < 2; ++ks) {
            const float* pr = &Pw[c15*68 + ks*32 + g*8];
            float4 plo = *(const float4*)pr;
            float4 phi = *(const float4*)(pr + 4);
            short8 pa;
            pa[0]=(short)f2bf(plo.x); pa[1]=(short)f2bf(plo.y);
            pa[2]=(short)f2bf(plo.z); pa[3]=(short)f2bf(plo.w);
            pa[4]=(short)f2bf(phi.x); pa[5]=(short)f2bf(phi.y);
            pa[6]=(short)f2bf(phi.z); pa[7]=(short)f2bf(phi.w);
            #pragma unroll
            for (int dt = 0; dt < 4; ++dt) {
                const int drow = dt*16 + c15;
                short8 vb = *(const short8*)&Vs[drow*64 + (((ks*4 + g) ^ (drow & 7)) * 8)];
                o[dt] = __builtin_amdgcn_mfma_f32_16x16x32_bf16(pa, vb, o[dt], 0, 0, 0);
            }
        }
    }

    float inv[4];
    #pragma unroll
    for (int reg = 0; reg < 4; ++reg) inv[reg] = 1.0f / l_run[reg];
    const int bb = bh >> 3, h = bh & 7;
    u16* cp = ctx + ((size_t)bb*L_ + qt*64 + w*16) * DM_ + h*DK_;
    #pragma unroll
    for (int dt = 0; dt < 4; ++dt)
        #pragma unroll
        for (int reg = 0; reg < 4; ++reg)
            cp[(size_t)(4*g + reg)*DM_ + dt*16 + c15] = f2bf(o[dt][reg] * inv[reg]);
}

// ---------------------------------------------------------------------------
extern "C" void kernel_launch(void* const* d_in, const int* in_sizes, int n_in,
                              void* d_out, int out_size, void* d_ws, size_t ws_size,
                              hipStream_t stream)
{
    const float* Q  = (const float*)d_in[0];
    const float* K  = (const float*)d_in[1];
    const float* V  = (const float*)d_in[2];
    const float* Wq = (const float*)d_in[3];
    const float* bq = (const float*)d_in[4];
    const float* Wk = (const float*)d_in[5];
    const float* bk = (const float*)d_in[6];
    const float* Wv = (const float*)d_in[7];
    const float* bv = (const float*)d_in[8];
    const float* Wo = (const float*)d_in[9];
    const float* bo = (const float*)d_in[10];
    // d_in[11] = index_sample: provably unused (n_top == L -> top_k is a
    // permutation -> the scatter overwrites the whole mean-context baseline).

    char* w8 = (char*)d_ws;
    const size_t MB = 1u << 20;
    u16* Qb  = (u16*)(w8);              // bf16 conversions (contiguous region)
    u16* Wqb = (u16*)(w8 + 12*MB);
    u16* Wkb = (u16*)(w8 + 12*MB + 512*1024);
    u16* Wvb = (u16*)(w8 + 13*MB);
    u16* Wob = (u16*)(w8 + 13*MB + 512*1024);
    u16* Kb  = (u16*)(w8 + 4*MB);
    u16* Vb  = (u16*)(w8 + 8*MB);
    u16* qw  = (u16*)(w8 + 14*MB);      // [B,H,L,DK] bf16, pre-scaled
    u16* kw  = (u16*)(w8 + 18*MB);      // [B,H,L,DK] bf16
    u16* vtw = (u16*)(w8 + 22*MB);      // [B,H,DK,L] bf16
    u16* cw  = (u16*)(w8 + 26*MB);      // [B*L, DM]  bf16 context

    cvt7<<<3584, 256, 0, stream>>>(Q, K, V, Wq, Wk, Wv, Wo, Qb);

    dim3 gg(64, 8), blk(256);
    gemm_mfma<1><<<gg, blk, 0, stream>>>(Qb, Wqb, bq, qw, SCALE_);
    gemm_mfma<1><<<gg, blk, 0, stream>>>(Kb, Wkb, bk, kw, 1.0f);
    gemm_mfma<2><<<gg, blk, 0, stream>>>(Vb, Wvb, bv, vtw, 1.0f);

    attn_mfma<<<dim3(32, 16), blk, 0, stream>>>(qw, kw, vtw, cw);

    gemm_mfma<0><<<gg, blk, 0, stream>>>(cw, Wob, bo, d_out, 1.0f);
}